// Round 1
// baseline (150.118 us; speedup 1.0000x reference)
//
#include <hip/hip_runtime.h>

// Problem constants (match reference): B=16, N=1024, D2H=1024, U=512
#define BB 16
#define NN 1024
#define DD 1024
#define UU 512

// ---------------------------------------------------------------------------
// Kernel A: v_h[d] = sum_u W_h[u,d]*w_out[u]; v_m likewise;
//           C = (b_h+b_m)·w_out + b_out  (scores = sH[i] + sM[j] + C)
// blocks 0..3 -> 1024 d-values (256 each); block 4 -> the scalar C.
// ---------------------------------------------------------------------------
__global__ __launch_bounds__(256) void prep_kernel(
    const float* __restrict__ W_h, const float* __restrict__ W_m,
    const float* __restrict__ b_h, const float* __restrict__ b_m,
    const float* __restrict__ w_out, const float* __restrict__ b_out,
    float* __restrict__ v_h, float* __restrict__ v_m, float* __restrict__ Cc) {
    __shared__ float w_s[UU];
    int t = threadIdx.x;
    // stage w_out in LDS (broadcast reuse)
    for (int u = t; u < UU; u += 256) w_s[u] = w_out[u];
    __syncthreads();

    if (blockIdx.x < 4) {
        int d = blockIdx.x * 256 + t;
        float ah = 0.f, am = 0.f;
        #pragma unroll 8
        for (int u = 0; u < UU; ++u) {
            float w = w_s[u];
            ah += W_h[(size_t)u * DD + d] * w;   // coalesced across threads
            am += W_m[(size_t)u * DD + d] * w;
        }
        v_h[d] = ah;
        v_m[d] = am;
    } else {
        __shared__ float red[256];
        float acc = 0.f;
        for (int u = t; u < UU; u += 256) acc += (b_h[u] + b_m[u]) * w_s[u];
        red[t] = acc;
        __syncthreads();
        for (int s = 128; s > 0; s >>= 1) {
            if (t < s) red[t] += red[t + s];
            __syncthreads();
        }
        if (t == 0) *Cc = red[0] + b_out[0];
    }
}

// ---------------------------------------------------------------------------
// Kernel B: sH[row] = x[row]·v_h ; sM[row] = x[row]·v_m   (row = b*N+n)
// One wave (64 lanes) per row; 4 waves per 256-thread block.
// float4 loads: 64 lanes * 4 float4 = 1024 floats = one row of x.
// ---------------------------------------------------------------------------
__global__ __launch_bounds__(256) void row_dots_kernel(
    const float* __restrict__ x,
    const float* __restrict__ v_h, const float* __restrict__ v_m,
    float* __restrict__ sH, float* __restrict__ sM) {
    __shared__ float4 vh_s[DD / 4];
    __shared__ float4 vm_s[DD / 4];
    int t = threadIdx.x;
    vh_s[t] = ((const float4*)v_h)[t];
    vm_s[t] = ((const float4*)v_m)[t];
    __syncthreads();

    int wave = t >> 6;
    int lane = t & 63;
    int row = blockIdx.x * 4 + wave;             // [0, B*N)
    const float4* xr = (const float4*)(x + (size_t)row * DD);

    float ah = 0.f, am = 0.f;
    #pragma unroll
    for (int k = 0; k < 4; ++k) {
        int idx = lane + 64 * k;
        float4 xv = xr[idx];
        float4 hv = vh_s[idx];
        float4 mv = vm_s[idx];
        ah += xv.x * hv.x + xv.y * hv.y + xv.z * hv.z + xv.w * hv.w;
        am += xv.x * mv.x + xv.y * mv.y + xv.z * mv.z + xv.w * mv.w;
    }
    // wave-64 butterfly reduction
    #pragma unroll
    for (int off = 32; off > 0; off >>= 1) {
        ah += __shfl_down(ah, off, 64);
        am += __shfl_down(am, off, 64);
    }
    if (lane == 0) {
        sH[row] = ah;
        sM[row] = am;
    }
}

// ---------------------------------------------------------------------------
// Kernel C: out[b,i,j] = sH[b*N+i] + sM[b*N+j] + C
// One block per (b,i) row: 256 threads x float4 = 1024 j's.
// sM row (4 KB) hits L1; sH[bi] is a broadcast; pure streaming store.
// ---------------------------------------------------------------------------
__global__ __launch_bounds__(256) void scores_kernel(
    const float* __restrict__ sH, const float* __restrict__ sM,
    const float* __restrict__ Cc, float4* __restrict__ out) {
    float C = *Cc;
    size_t t = (size_t)blockIdx.x * 256 + threadIdx.x;   // float4 index
    size_t idx = t << 2;                                  // flat [B,N,N] index
    int bi = (int)(idx >> 10);                            // b*N + i
    int j  = (int)(idx & 1023);
    float h = sH[bi] + C;
    float4 m = *(const float4*)(sM + (bi & ~1023) + j);   // b*N + j
    float4 o;
    o.x = h + m.x;
    o.y = h + m.y;
    o.z = h + m.z;
    o.w = h + m.w;
    out[t] = o;
}

extern "C" void kernel_launch(void* const* d_in, const int* in_sizes, int n_in,
                              void* d_out, int out_size, void* d_ws, size_t ws_size,
                              hipStream_t stream) {
    const float* x     = (const float*)d_in[0];
    const float* W_h   = (const float*)d_in[1];
    const float* b_h   = (const float*)d_in[2];
    const float* W_m   = (const float*)d_in[3];
    const float* b_m   = (const float*)d_in[4];
    const float* w_out = (const float*)d_in[5];
    const float* b_out = (const float*)d_in[6];
    float* out = (float*)d_out;

    float* ws  = (float*)d_ws;
    float* sH  = ws;               // B*N = 16384
    float* sM  = ws + 16384;       // B*N = 16384
    float* v_h = ws + 32768;       // D = 1024
    float* v_m = ws + 33792;       // D = 1024
    float* Cc  = ws + 34816;       // 1

    prep_kernel<<<5, 256, 0, stream>>>(W_h, W_m, b_h, b_m, w_out, b_out, v_h, v_m, Cc);
    row_dots_kernel<<<BB * NN / 4, 256, 0, stream>>>(x, v_h, v_m, sH, sM);
    scores_kernel<<<(size_t)BB * NN * NN / 1024, 256, 0, stream>>>(sH, sM, Cc, (float4*)out);
}

// Round 2
// 127.586 us; speedup vs baseline: 1.1766x; 1.1766x over previous
//
#include <hip/hip_runtime.h>

// Problem constants (match reference): B=16, N=1024, D2H=1024, U=512
#define BB 16
#define NN 1024
#define DD 1024
#define UU 512

// ---------------------------------------------------------------------------
// Kernel A: v_h[d] = sum_u W_h[u,d]*w_out[u]; v_m likewise;
//           C = (b_h+b_m)·w_out + b_out.
// 129 blocks: 0..63 -> W_h (4 d-chunks x 16 u-chunks), 64..127 -> W_m,
// 128 -> scalar C. Partials combined via atomicAdd into zeroed v_h/v_m.
// ---------------------------------------------------------------------------
__global__ __launch_bounds__(256) void prep_kernel(
    const float* __restrict__ W_h, const float* __restrict__ W_m,
    const float* __restrict__ b_h, const float* __restrict__ b_m,
    const float* __restrict__ w_out, const float* __restrict__ b_out,
    float* __restrict__ v_h, float* __restrict__ v_m, float* __restrict__ Cc) {
    int t = threadIdx.x;
    int blk = blockIdx.x;
    if (blk < 128) {
        const float* W = (blk < 64) ? W_h : W_m;
        float* v = (blk < 64) ? v_h : v_m;
        int b = blk & 63;
        int d = (b & 3) * 256 + t;      // 4 chunks of 256 d
        int u0 = (b >> 2) * 32;         // 16 chunks of 32 u
        float acc = 0.f;
        #pragma unroll
        for (int k = 0; k < 32; ++k) {
            // w_out[u0+k] is wave-uniform -> scalar load; W access coalesced in d
            acc += W[(size_t)(u0 + k) * DD + d] * w_out[u0 + k];
        }
        atomicAdd(v + d, acc);
    } else {
        __shared__ float red[256];
        float acc = 0.f;
        for (int u = t; u < UU; u += 256) acc += (b_h[u] + b_m[u]) * w_out[u];
        red[t] = acc;
        __syncthreads();
        for (int s = 128; s > 0; s >>= 1) {
            if (t < s) red[t] += red[t + s];
            __syncthreads();
        }
        if (t == 0) *Cc = red[0] + b_out[0];
    }
}

// ---------------------------------------------------------------------------
// Kernel B: sH[row] = x[row]·v_h + C ; sM[row] = x[row]·v_m   (row = b*N+n)
// One wave per row, 4 waves/block. v_h/v_m read straight from L2 (4 KB each,
// XCD-resident) — no LDS staging, no barrier. C folded into sH.
// ---------------------------------------------------------------------------
__global__ __launch_bounds__(256) void row_dots_kernel(
    const float* __restrict__ x,
    const float* __restrict__ v_h, const float* __restrict__ v_m,
    const float* __restrict__ Cc,
    float* __restrict__ sH, float* __restrict__ sM) {
    int t = threadIdx.x;
    int wave = t >> 6, lane = t & 63;
    int row = blockIdx.x * 4 + wave;                 // [0, B*N)
    const float4* xr = (const float4*)(x + (size_t)row * DD);
    const float4* vh = (const float4*)v_h;
    const float4* vm = (const float4*)v_m;

    float ah = 0.f, am = 0.f;
    #pragma unroll
    for (int k = 0; k < 4; ++k) {
        int idx = lane + 64 * k;
        float4 xv = xr[idx];
        float4 hv = vh[idx];
        float4 mv = vm[idx];
        ah += xv.x * hv.x + xv.y * hv.y + xv.z * hv.z + xv.w * hv.w;
        am += xv.x * mv.x + xv.y * mv.y + xv.z * mv.z + xv.w * mv.w;
    }
    #pragma unroll
    for (int off = 32; off > 0; off >>= 1) {
        ah += __shfl_down(ah, off, 64);
        am += __shfl_down(am, off, 64);
    }
    if (lane == 0) {
        sH[row] = ah + *Cc;   // fold the scalar offset here
        sM[row] = am;
    }
}

// ---------------------------------------------------------------------------
// Kernel C: out[b,i,j] = sH[b*N+i] + sM[b*N+j]   (C already inside sH)
// One block per (b,i): sH[bi] is a scalar broadcast, sM row (4 KB) L1/L2-hot,
// one float4 streaming store per thread.
// ---------------------------------------------------------------------------
__global__ __launch_bounds__(256) void scores_kernel(
    const float* __restrict__ sH, const float* __restrict__ sM,
    float4* __restrict__ out) {
    int bi = blockIdx.x;                              // b*N + i
    int j4 = threadIdx.x;                             // float4 index in row
    float h = sH[bi];
    const float4* mrow = (const float4*)(sM + (bi & ~(NN - 1)));
    float4 m = mrow[j4];
    float4 o;
    o.x = h + m.x;
    o.y = h + m.y;
    o.z = h + m.z;
    o.w = h + m.w;
    out[(size_t)bi * (NN / 4) + j4] = o;
}

extern "C" void kernel_launch(void* const* d_in, const int* in_sizes, int n_in,
                              void* d_out, int out_size, void* d_ws, size_t ws_size,
                              hipStream_t stream) {
    const float* x     = (const float*)d_in[0];
    const float* W_h   = (const float*)d_in[1];
    const float* b_h   = (const float*)d_in[2];
    const float* W_m   = (const float*)d_in[3];
    const float* b_m   = (const float*)d_in[4];
    const float* w_out = (const float*)d_in[5];
    const float* b_out = (const float*)d_in[6];
    float* out = (float*)d_out;

    float* ws  = (float*)d_ws;
    float* v_h = ws;               // 1024
    float* v_m = ws + 1024;        // 1024
    float* Cc  = ws + 2048;        // 1
    float* sH  = ws + 4096;        // B*N = 16384
    float* sM  = ws + 4096 + 16384;

    // zero the atomicAdd targets (ws is poisoned 0xAA before every call)
    hipMemsetAsync(ws, 0, 2048 * sizeof(float), stream);

    prep_kernel<<<129, 256, 0, stream>>>(W_h, W_m, b_h, b_m, w_out, b_out, v_h, v_m, Cc);
    row_dots_kernel<<<BB * NN / 4, 256, 0, stream>>>(x, v_h, v_m, Cc, sH, sM);
    scores_kernel<<<BB * NN, 256, 0, stream>>>(sH, sM, (float4*)out);
}